// Round 5
// baseline (1093.863 us; speedup 1.0000x reference)
//
#include <hip/hip_runtime.h>
#include <math.h>

// Problem dims
#define BD 64
#define TD 128
#define HD 300
#define NROW (2*BD*TD)          // 16384 rows (both trees)
#define ROWSZ ((size_t)NROW*HD) // per-array floats
#define CMAX 32                 // max children per node (mean ~6.4 at 5%)
#define AMAX 64                 // max (in+out) neighbors per node in GCN

__device__ __forceinline__ float sigf(float x){ return 1.f/(1.f+expf(-x)); }

// ---------------------------------------------------------------------------
// Fused 4-gate GEMM over gathered embedding rows.
//   pre_g[r,n] = emb[tok[r],:] . Wg[n,:] + wg_b[n] + ug_b[n]   (g = i,f,o,u)
//   IU = sigmoid(pre_i) * tanh(pre_u); Og = sigmoid(pre_o); F0 = pre_f (raw)
// Tiles: 64 rows x 64 cols, BK=32, 256 threads, per-thread 4x4 per gate.
// ---------------------------------------------------------------------------
__global__ __launch_bounds__(256) void gates_gemm_k(
    const int* __restrict__ tokL, const int* __restrict__ tokR,
    const float* __restrict__ emb,
    const float* __restrict__ wi_w, const float* __restrict__ wf_w,
    const float* __restrict__ wo_w, const float* __restrict__ wu_w,
    const float* __restrict__ wi_b, const float* __restrict__ ui_b,
    const float* __restrict__ wf_b, const float* __restrict__ uf_b,
    const float* __restrict__ wo_b, const float* __restrict__ uo_b,
    const float* __restrict__ wu_b, const float* __restrict__ uu_b,
    float* __restrict__ IU, float* __restrict__ Og, float* __restrict__ F0)
{
  __shared__ __align__(16) float As[32][64];
  __shared__ __align__(16) float Bs[4][32][64];
  const int r0 = blockIdx.x * 64;
  const int n0 = blockIdx.y * 64;
  const int tid = threadIdx.x;

  // A rows via token gather
  const int am  = tid >> 2;    // 0..63
  const int akq = tid & 3;     // 0..3
  const float* arow;
  {
    int r = r0 + am;
    int tree = r >> 13;
    int tok  = (tree ? tokR : tokL)[r & 8191];
    arow = emb + (size_t)tok * HD;
  }

  const float* Bm[4] = {wi_w, wf_w, wo_w, wu_w};
  const int bn  = tid >> 2;    // 0..63 (col within tile)
  const int bkq = tid & 3;
  const bool nok = (n0 + bn) < HD;

  const int tm = tid >> 4;     // 0..15
  const int tn = tid & 15;     // 0..15
  float acc[4][4][4] = {};     // [gate][i][j]

  for (int k0 = 0; k0 < HD; k0 += 32){
    // ---- stage A tile: As[k][m]
    #pragma unroll
    for (int h = 0; h < 2; ++h){
      int k  = akq*8 + h*4;
      int kg = k0 + k;
      float4 v;
      if (kg + 3 < HD) v = *(const float4*)(arow + kg);
      else {
        v.x = (kg   < HD) ? arow[kg]   : 0.f;
        v.y = (kg+1 < HD) ? arow[kg+1] : 0.f;
        v.z = (kg+2 < HD) ? arow[kg+2] : 0.f;
        v.w = (kg+3 < HD) ? arow[kg+3] : 0.f;
      }
      As[k+0][am] = v.x; As[k+1][am] = v.y; As[k+2][am] = v.z; As[k+3][am] = v.w;
    }
    // ---- stage 4 B tiles: Bs[g][k][n]  (weights are (N,K) row-major)
    #pragma unroll
    for (int g = 0; g < 4; ++g){
      const float* brow = Bm[g] + (size_t)(n0 + bn) * HD;
      #pragma unroll
      for (int h = 0; h < 2; ++h){
        int k  = bkq*8 + h*4;
        int kg = k0 + k;
        float4 v = {0.f,0.f,0.f,0.f};
        if (nok){
          if (kg + 3 < HD) v = *(const float4*)(brow + kg);
          else {
            if (kg   < HD) v.x = brow[kg];
            if (kg+1 < HD) v.y = brow[kg+1];
            if (kg+2 < HD) v.z = brow[kg+2];
          }
        }
        Bs[g][k+0][bn] = v.x; Bs[g][k+1][bn] = v.y;
        Bs[g][k+2][bn] = v.z; Bs[g][k+3][bn] = v.w;
      }
    }
    __syncthreads();

    #pragma unroll 8
    for (int k = 0; k < 32; ++k){
      float a[4];
      *(float4*)a = *(const float4*)&As[k][tm*4];
      #pragma unroll
      for (int g = 0; g < 4; ++g){
        float bb[4];
        *(float4*)bb = *(const float4*)&Bs[g][k][tn*4];
        #pragma unroll
        for (int i = 0; i < 4; ++i)
          #pragma unroll
          for (int j = 0; j < 4; ++j)
            acc[g][i][j] += a[i]*bb[j];
      }
    }
    __syncthreads();
  }

  // epilogue: gate math + 3 stores
  #pragma unroll
  for (int j = 0; j < 4; ++j){
    int col = n0 + tn*4 + j;
    if (col >= HD) continue;
    float bi = wi_b[col] + ui_b[col];
    float bf = wf_b[col] + uf_b[col];
    float bo = wo_b[col] + uo_b[col];
    float bu = wu_b[col] + uu_b[col];
    #pragma unroll
    for (int i = 0; i < 4; ++i){
      int r = r0 + tm*4 + i;
      size_t idx = (size_t)r * HD + col;
      float ii = sigf(acc[0][i][j] + bi);
      float uu = tanhf(acc[3][i][j] + bu);
      IU[idx] = ii * uu;
      Og[idx] = sigf(acc[2][i][j] + bo);
      F0[idx] = acc[1][i][j] + bf;
    }
  }
}

// ---------------------------------------------------------------------------
// Plain tiled fp32 GEMM (used for GCN: C = A @ B, B is (K,N) row-major).
// ---------------------------------------------------------------------------
__global__ __launch_bounds__(256) void gemm_nn_k(
    const float* __restrict__ A, const float* __restrict__ B,
    float* __restrict__ C)
{
  __shared__ __align__(16) float As[32][64];
  __shared__ __align__(16) float Bs[32][64];
  const int r0 = blockIdx.x * 64;
  const int n0 = blockIdx.y * 64;
  const int tid = threadIdx.x;

  const int am  = tid >> 2;
  const int akq = tid & 3;
  const float* arow = A + (size_t)(r0 + am) * HD;

  const int tm = tid >> 4;
  const int tn = tid & 15;
  float acc[4][4] = {};

  for (int k0 = 0; k0 < HD; k0 += 32){
    #pragma unroll
    for (int h = 0; h < 2; ++h){
      int k  = akq*8 + h*4;
      int kg = k0 + k;
      float4 v;
      if (kg + 3 < HD) v = *(const float4*)(arow + kg);
      else {
        v.x = (kg   < HD) ? arow[kg]   : 0.f;
        v.y = (kg+1 < HD) ? arow[kg+1] : 0.f;
        v.z = (kg+2 < HD) ? arow[kg+2] : 0.f;
        v.w = (kg+3 < HD) ? arow[kg+3] : 0.f;
      }
      As[k+0][am] = v.x; As[k+1][am] = v.y; As[k+2][am] = v.z; As[k+3][am] = v.w;
    }
    {
      int bk  = tid >> 3;    // 0..31
      int bnq = tid & 7;     // 0..7
      int kg  = k0 + bk;
      const float* brow = B + (size_t)kg * HD;
      #pragma unroll
      for (int h = 0; h < 2; ++h){
        int n  = bnq*8 + h*4;
        int ng = n0 + n;
        float4 v = {0.f,0.f,0.f,0.f};
        if (kg < HD){
          if (ng + 3 < HD) v = *(const float4*)(brow + ng);
          else {
            if (ng   < HD) v.x = brow[ng];
            if (ng+1 < HD) v.y = brow[ng+1];
            if (ng+2 < HD) v.z = brow[ng+2];
          }
        }
        *(float4*)&Bs[bk][n] = v;
      }
    }
    __syncthreads();

    #pragma unroll 8
    for (int k = 0; k < 32; ++k){
      float a[4], bb[4];
      *(float4*)a  = *(const float4*)&As[k][tm*4];
      *(float4*)bb = *(const float4*)&Bs[k][tn*4];
      #pragma unroll
      for (int i = 0; i < 4; ++i)
        #pragma unroll
        for (int j = 0; j < 4; ++j)
          acc[i][j] += a[i]*bb[j];
    }
    __syncthreads();
  }

  #pragma unroll
  for (int i = 0; i < 4; ++i){
    int r = r0 + tm*4 + i;
    #pragma unroll
    for (int j = 0; j < 4; ++j){
      int col = n0 + tn*4 + j;
      if (col < HD) C[(size_t)r * HD + col] = acc[i][j];
    }
  }
}

// ---------------------------------------------------------------------------
// LEVEL-SCHEDULED recurrence: one workgroup per (tree, b) chain.
// hj == 0 in the reference, so i,o,u are precomputed; remaining deps:
//   c[j] = IU[j] + sum_{t in children(j)} m * sig(F0[j] + g[t]) * c[t]
//   h[j] = Og[j] * tanh(c[j]);  g[j] = uf_w . h[j]
// Nodes grouped by DAG depth (level); nodes within a level are independent
// (an edge j->t forces level[j] > level[t]). Expected depth ~18 << 128.
// RUNS IN PLACE: c over IU, h over Og, g over F0 (each element read strictly
// before overwrite; children rows belong to earlier levels).
// ---------------------------------------------------------------------------
__global__ __launch_bounds__(320) void recurrence_k(
    float* IU_C,      // in: IU  / out: c
    float* Og_H,      // in: Og  / out: h
    float* F0_G,      // in: F0  / out: g
    const float* __restrict__ gL, const float* __restrict__ gR,
    const float* __restrict__ ufw)
{
  const int wg   = blockIdx.x;
  const int tree = wg >> 6;
  const int b    = wg & 63;
  const float* graph = tree ? gR : gL;
  const int tid = threadIdx.x;

  __shared__ float  cw  [TD][CMAX];            // 16 KB
  __shared__ unsigned char cidx[TD][CMAX];     // 4 KB
  __shared__ int    ccnt[TD];
  __shared__ int    lvl [TD];
  __shared__ int    cnt [TD+1];
  __shared__ int    cur [TD+1];
  __shared__ int    lvstart[TD+1];
  __shared__ int    order[TD];
  __shared__ int    changed, nlv_s;
  __shared__ __align__(16) float hl[32][HD];   // 38.4 KB (total ~62 KB)

  // ---- compact child lists: thread j scans graph row j (tril -> t<j only)
  if (tid < TD){
    const int j = tid;
    const float* grow = graph + ((size_t)b*TD + j)*TD;
    int c = 0;
    for (int t = 0; t < j; ++t){
      float m = grow[t];
      if (m != 0.f && c < CMAX){ cidx[j][c] = (unsigned char)t; cw[j][c] = m; ++c; }
    }
    ccnt[j] = c;
    lvl[j] = 0;
  }
  __syncthreads();

  // ---- levels by Jacobi relaxation (monotone; converges in depth rounds)
  for (int it = 0; it < TD; ++it){
    if (tid == 0) changed = 0;
    __syncthreads();
    if (tid < TD){
      int m = 0, cn = ccnt[tid];
      for (int li = 0; li < cn; ++li){
        int lc = lvl[cidx[tid][li]] + 1;
        m = m > lc ? m : lc;
      }
      if (m > lvl[tid]){ lvl[tid] = m; changed = 1; }
    }
    __syncthreads();
    int ch = changed;
    __syncthreads();            // protect 'changed' before next-iter reset
    if (!ch) break;
  }

  // ---- counting sort by level
  if (tid == 0) nlv_s = 0;
  for (int q = tid; q <= TD; q += 320){ cnt[q] = 0; }
  __syncthreads();
  if (tid < TD){
    atomicMax(&nlv_s, lvl[tid] + 1);
    atomicAdd(&cnt[lvl[tid]], 1);
  }
  __syncthreads();
  const int nlv = nlv_s;
  if (tid == 0){
    int run = 0;
    for (int lv = 0; lv < nlv; ++lv){
      lvstart[lv] = run; cur[lv] = run; run += cnt[lv];
    }
    lvstart[nlv] = run;   // == TD
  }
  __syncthreads();
  if (tid < TD){
    int p = atomicAdd(&cur[lvl[tid]], 1);
    order[p] = tid;
  }
  __syncthreads();

  const size_t base = (size_t)(tree*BD + b) * TD * HD;

  // ---- main loop over levels
  for (int lv = 0; lv < nlv; ++lv){
    const int s = lvstart[lv], e = lvstart[lv+1];
    const bool doB = (lv != nlv - 1);   // max-level nodes have no parents
    for (int cs0 = s; cs0 < e; cs0 += 32){
      const int csn = (e - cs0) < 32 ? (e - cs0) : 32;

      // Phase A: c,h for all nodes of this chunk (independent)
      for (int q = tid; q < csn*HD; q += 320){
        int ni = q / HD;
        int d  = q - ni*HD;
        int j  = order[cs0 + ni];
        size_t rj = base + (size_t)j*HD + d;
        float f0  = F0_G[rj];
        float acc = 0.f;
        const int cn = ccnt[j];
        for (int li = 0; li < cn; ++li){
          int t = cidx[j][li];
          size_t rt = base + (size_t)t*HD + d;
          acc += cw[j][li] * sigf(f0 + F0_G[rt]) * IU_C[rt];   // g[t], c[t]
        }
        float c = IU_C[rj] + acc;
        float h = Og_H[rj] * tanhf(c);
        IU_C[rj] = c; Og_H[rj] = h; hl[ni][d] = h;
      }
      __syncthreads();

      // Phase B: g = uf_w . h for the chunk, 8 nodes per pass
      if (doB){
        for (int nb0 = 0; nb0 < csn; nb0 += 8){
          if (tid < HD){
            const int d = tid;
            const float4* wrow = (const float4*)(ufw + (size_t)d * HD);
            float acc[8];
            #pragma unroll
            for (int ni = 0; ni < 8; ++ni) acc[ni] = 0.f;
            for (int k4 = 0; k4 < HD/4; ++k4){
              float4 w = wrow[k4];
              #pragma unroll
              for (int ni = 0; ni < 8; ++ni){
                // rows nb0+ni <= 31 always (csn<=32, nb0 multiple of 8)
                float4 h4 = *(const float4*)&hl[nb0+ni][k4*4];
                acc[ni] += w.x*h4.x + w.y*h4.y + w.z*h4.z + w.w*h4.w;
              }
            }
            #pragma unroll
            for (int ni = 0; ni < 8; ++ni){
              if (nb0 + ni < csn){
                int j = order[cs0 + nb0 + ni];
                F0_G[base + (size_t)j*HD + d] = acc[ni];   // g[j] over F0[j]
              }
            }
          }
        }
      }
      __syncthreads();   // hl reusable; g visible before next level
    }
  }
}

// ---------------------------------------------------------------------------
// GCN aggregate (A = I + G + G^T, sparse) + relu + max/mean pooling.
// One workgroup per (tree,b). Graph staged in LDS (padded: column reads
// conflict-free); neighbor lists precomputed once -> barrier-free main loop.
// Writes v[b, tree*300 + d] (max) and v[b, 600 + tree*300 + d] (mean).
// ---------------------------------------------------------------------------
__global__ __launch_bounds__(320) void gcn_pool_k(
    const float* __restrict__ HG,
    const float* __restrict__ gL, const float* __restrict__ gR,
    float* __restrict__ vbuf)
{
  const int wg   = blockIdx.x;
  const int tree = wg >> 6;
  const int b    = wg & 63;
  const float* graph = tree ? gR : gL;
  const int tid = threadIdx.x;

  __shared__ float gl[TD][TD+1];               // 66 KB padded
  __shared__ float aw[TD][AMAX];               // 32 KB
  __shared__ unsigned char ai[TD][AMAX];       // 8 KB
  __shared__ int   acnt[TD];

  for (int q = tid; q < TD*TD; q += 320)
    gl[q >> 7][q & 127] = graph[(size_t)b*TD*TD + q];
  __syncthreads();

  // neighbor lists: thread s compacts w[t] = G[s,t] + G[t,s]
  if (tid < TD){
    const int s = tid;
    int c = 0;
    for (int t = 0; t < TD; ++t){
      float w = gl[s][t] + gl[t][s];
      if (w != 0.f && c < AMAX){ ai[s][c] = (unsigned char)t; aw[s][c] = w; ++c; }
    }
    acnt[s] = c;
  }
  __syncthreads();

  const size_t base = (size_t)(tree*BD + b) * TD * HD;
  if (tid < HD){
    float mx = -3.4e38f, sm = 0.f;
    for (int s = 0; s < TD; ++s){
      float v = HG[base + (size_t)s*HD + tid];
      const int cn = acnt[s];
      for (int li = 0; li < cn; ++li)
        v += aw[s][li] * HG[base + (size_t)ai[s][li]*HD + tid];
      v = fmaxf(v, 0.f);
      mx = fmaxf(mx, v);
      sm += v;
    }
    vbuf[(size_t)b*1200 + tree*HD + tid]       = mx;
    vbuf[(size_t)b*1200 + 600 + tree*HD + tid] = sm * (1.f/128.f);
  }
}

// ---------------------------------------------------------------------------
// Classifier: out[b] = wp . relu(wh . v[b] + wh_b) + wp_b
// ---------------------------------------------------------------------------
__global__ __launch_bounds__(320) void classifier_k(
    const float* __restrict__ vbuf,
    const float* __restrict__ wh_w, const float* __restrict__ wh_b,
    const float* __restrict__ wp_w, const float* __restrict__ wp_b,
    float* __restrict__ out)
{
  const int b = blockIdx.x;
  const int tid = threadIdx.x;
  __shared__ __align__(16) float vrow[1200];
  __shared__ float hid[300];
  __shared__ float red[5];

  for (int m = tid; m < 1200; m += 320) vrow[m] = vbuf[(size_t)b*1200 + m];
  __syncthreads();

  if (tid < HD){
    const float4* wrow = (const float4*)(wh_w + (size_t)tid*1200);
    float a0 = wh_b[tid], a1 = 0.f, a2 = 0.f, a3 = 0.f;
    #pragma unroll 5
    for (int m4 = 0; m4 < 300; ++m4){
      float4 w = wrow[m4];
      float4 v = *(const float4*)&vrow[m4*4];
      a0 += w.x*v.x; a1 += w.y*v.y; a2 += w.z*v.z; a3 += w.w*v.w;
    }
    hid[tid] = fmaxf((a0+a1)+(a2+a3), 0.f);
  }
  __syncthreads();

  const int wave = tid >> 6, lane = tid & 63;
  for (int n = 0; n < 3; ++n){
    float p = (tid < HD) ? wp_w[n*HD + tid] * hid[tid] : 0.f;
    #pragma unroll
    for (int off = 32; off > 0; off >>= 1) p += __shfl_down(p, off);
    if (lane == 0) red[wave] = p;
    __syncthreads();
    if (tid == 0){
      float s = wp_b[n];
      for (int wv = 0; wv < 5; ++wv) s += red[wv];
      out[(size_t)b*3 + n] = s;
    }
    __syncthreads();
  }
}

// ---------------------------------------------------------------------------
extern "C" void kernel_launch(void* const* d_in, const int* in_sizes, int n_in,
                              void* d_out, int out_size, void* d_ws, size_t ws_size,
                              hipStream_t stream) {
  const int*   linputs = (const int*)  d_in[0];
  const float* lgraph  = (const float*)d_in[1];
  const int*   rinputs = (const int*)  d_in[2];
  const float* rgraph  = (const float*)d_in[3];
  const float* emb     = (const float*)d_in[4];
  const float* wi_w = (const float*)d_in[5],  *wi_b = (const float*)d_in[6];
  const float* wf_w = (const float*)d_in[7],  *wf_b = (const float*)d_in[8];
  const float* wo_w = (const float*)d_in[9],  *wo_b = (const float*)d_in[10];
  const float* wu_w = (const float*)d_in[11], *wu_b = (const float*)d_in[12];
  const float* ui_b = (const float*)d_in[14];
  const float* uf_w = (const float*)d_in[15], *uf_b = (const float*)d_in[16];
  const float* uo_b = (const float*)d_in[18];
  const float* uu_b = (const float*)d_in[20];
  const float* gcn_w = (const float*)d_in[21];
  const float* wh_w  = (const float*)d_in[22], *wh_b = (const float*)d_in[23];
  const float* wp_w  = (const float*)d_in[24], *wp_b = (const float*)d_in[25];

  // Workspace layout (floats). In-place recurrence: buf0 IU->c, buf1 Og->h,
  // buf2 F0->g. After recurrence buf0 (c) is dead -> reused for HG.
  float* ws   = (float*)d_ws;
  float* buf0 = ws;               // IU -> c -> HG
  float* buf1 = ws + 1*ROWSZ;     // Og -> h
  float* buf2 = ws + 2*ROWSZ;     // F0 -> g
  float* vbuf = ws + 3*ROWSZ;     // 64*1200
  float* out  = (float*)d_out;

  dim3 gg(NROW/64, 5);
  gates_gemm_k<<<gg,256,0,stream>>>(linputs, rinputs, emb,
      wi_w, wf_w, wo_w, wu_w,
      wi_b, ui_b, wf_b, uf_b, wo_b, uo_b, wu_b, uu_b,
      buf0, buf1, buf2);

  recurrence_k<<<128,320,0,stream>>>(buf0, buf1, buf2, lgraph, rgraph, uf_w);

  // HG = H @ gcn_w   (H in buf1; HG overwrites buf0 — c is dead)
  gemm_nn_k<<<gg,256,0,stream>>>(buf1, gcn_w, buf0);

  gcn_pool_k<<<128,320,0,stream>>>(buf0, lgraph, rgraph, vbuf);
  classifier_k<<<64,320,0,stream>>>(vbuf, wh_w, wh_b, wp_w, wp_b, out);

  (void)in_sizes; (void)n_in; (void)out_size; (void)ws_size;
}

// Round 9
// 913.770 us; speedup vs baseline: 1.1971x; 1.1971x over previous
//
#include <hip/hip_runtime.h>
#include <math.h>

// Problem dims
#define BD 64
#define TD 128
#define HD 300
#define NROW (2*BD*TD)          // 16384 rows (both trees)
#define ROWSZ ((size_t)NROW*HD) // per-array floats
#define CMAX 32                 // max children per node (mean ~6.4 at 5%)
#define AMAX 64                 // max (in+out) neighbors per node in GCN
#define RTHREADS 960            // recurrence threads (15 waves)

__device__ __forceinline__ float sigf(float x){ return 1.f/(1.f+expf(-x)); }

// ---------------------------------------------------------------------------
// Fused 4-gate GEMM over gathered embedding rows.
// ---------------------------------------------------------------------------
__global__ __launch_bounds__(256) void gates_gemm_k(
    const int* __restrict__ tokL, const int* __restrict__ tokR,
    const float* __restrict__ emb,
    const float* __restrict__ wi_w, const float* __restrict__ wf_w,
    const float* __restrict__ wo_w, const float* __restrict__ wu_w,
    const float* __restrict__ wi_b, const float* __restrict__ ui_b,
    const float* __restrict__ wf_b, const float* __restrict__ uf_b,
    const float* __restrict__ wo_b, const float* __restrict__ uo_b,
    const float* __restrict__ wu_b, const float* __restrict__ uu_b,
    float* __restrict__ IU, float* __restrict__ Og, float* __restrict__ F0)
{
  __shared__ __align__(16) float As[32][64];
  __shared__ __align__(16) float Bs[4][32][64];
  const int r0 = blockIdx.x * 64;
  const int n0 = blockIdx.y * 64;
  const int tid = threadIdx.x;

  const int am  = tid >> 2;    // 0..63
  const int akq = tid & 3;     // 0..3
  const float* arow;
  {
    int r = r0 + am;
    int tree = r >> 13;
    int tok  = (tree ? tokR : tokL)[r & 8191];
    arow = emb + (size_t)tok * HD;
  }

  const float* Bm[4] = {wi_w, wf_w, wo_w, wu_w};
  const int bn  = tid >> 2;    // 0..63
  const int bkq = tid & 3;
  const bool nok = (n0 + bn) < HD;

  const int tm = tid >> 4;     // 0..15
  const int tn = tid & 15;     // 0..15
  float acc[4][4][4] = {};     // [gate][i][j]

  for (int k0 = 0; k0 < HD; k0 += 32){
    #pragma unroll
    for (int h = 0; h < 2; ++h){
      int k  = akq*8 + h*4;
      int kg = k0 + k;
      float4 v;
      if (kg + 3 < HD) v = *(const float4*)(arow + kg);
      else {
        v.x = (kg   < HD) ? arow[kg]   : 0.f;
        v.y = (kg+1 < HD) ? arow[kg+1] : 0.f;
        v.z = (kg+2 < HD) ? arow[kg+2] : 0.f;
        v.w = (kg+3 < HD) ? arow[kg+3] : 0.f;
      }
      As[k+0][am] = v.x; As[k+1][am] = v.y; As[k+2][am] = v.z; As[k+3][am] = v.w;
    }
    #pragma unroll
    for (int g = 0; g < 4; ++g){
      const float* brow = Bm[g] + (size_t)(n0 + bn) * HD;
      #pragma unroll
      for (int h = 0; h < 2; ++h){
        int k  = bkq*8 + h*4;
        int kg = k0 + k;
        float4 v = {0.f,0.f,0.f,0.f};
        if (nok){
          if (kg + 3 < HD) v = *(const float4*)(brow + kg);
          else {
            if (kg   < HD) v.x = brow[kg];
            if (kg+1 < HD) v.y = brow[kg+1];
            if (kg+2 < HD) v.z = brow[kg+2];
          }
        }
        Bs[g][k+0][bn] = v.x; Bs[g][k+1][bn] = v.y;
        Bs[g][k+2][bn] = v.z; Bs[g][k+3][bn] = v.w;
      }
    }
    __syncthreads();

    #pragma unroll 8
    for (int k = 0; k < 32; ++k){
      float a[4];
      *(float4*)a = *(const float4*)&As[k][tm*4];
      #pragma unroll
      for (int g = 0; g < 4; ++g){
        float bb[4];
        *(float4*)bb = *(const float4*)&Bs[g][k][tn*4];
        #pragma unroll
        for (int i = 0; i < 4; ++i)
          #pragma unroll
          for (int j = 0; j < 4; ++j)
            acc[g][i][j] += a[i]*bb[j];
      }
    }
    __syncthreads();
  }

  #pragma unroll
  for (int j = 0; j < 4; ++j){
    int col = n0 + tn*4 + j;
    if (col >= HD) continue;
    float bi = wi_b[col] + ui_b[col];
    float bf = wf_b[col] + uf_b[col];
    float bo = wo_b[col] + uo_b[col];
    float bu = wu_b[col] + uu_b[col];
    #pragma unroll
    for (int i = 0; i < 4; ++i){
      int r = r0 + tm*4 + i;
      size_t idx = (size_t)r * HD + col;
      float ii = sigf(acc[0][i][j] + bi);
      float uu = tanhf(acc[3][i][j] + bu);
      IU[idx] = ii * uu;
      Og[idx] = sigf(acc[2][i][j] + bo);
      F0[idx] = acc[1][i][j] + bf;
    }
  }
}

// ---------------------------------------------------------------------------
// Plain tiled fp32 GEMM (GCN: C = A @ B, B (K,N) row-major).
// ---------------------------------------------------------------------------
__global__ __launch_bounds__(256) void gemm_nn_k(
    const float* __restrict__ A, const float* __restrict__ B,
    float* __restrict__ C)
{
  __shared__ __align__(16) float As[32][64];
  __shared__ __align__(16) float Bs[32][64];
  const int r0 = blockIdx.x * 64;
  const int n0 = blockIdx.y * 64;
  const int tid = threadIdx.x;

  const int am  = tid >> 2;
  const int akq = tid & 3;
  const float* arow = A + (size_t)(r0 + am) * HD;

  const int tm = tid >> 4;
  const int tn = tid & 15;
  float acc[4][4] = {};

  for (int k0 = 0; k0 < HD; k0 += 32){
    #pragma unroll
    for (int h = 0; h < 2; ++h){
      int k  = akq*8 + h*4;
      int kg = k0 + k;
      float4 v;
      if (kg + 3 < HD) v = *(const float4*)(arow + kg);
      else {
        v.x = (kg   < HD) ? arow[kg]   : 0.f;
        v.y = (kg+1 < HD) ? arow[kg+1] : 0.f;
        v.z = (kg+2 < HD) ? arow[kg+2] : 0.f;
        v.w = (kg+3 < HD) ? arow[kg+3] : 0.f;
      }
      As[k+0][am] = v.x; As[k+1][am] = v.y; As[k+2][am] = v.z; As[k+3][am] = v.w;
    }
    {
      int bk  = tid >> 3;    // 0..31
      int bnq = tid & 7;     // 0..7
      int kg  = k0 + bk;
      const float* brow = B + (size_t)kg * HD;
      #pragma unroll
      for (int h = 0; h < 2; ++h){
        int n  = bnq*8 + h*4;
        int ng = n0 + n;
        float4 v = {0.f,0.f,0.f,0.f};
        if (kg < HD){
          if (ng + 3 < HD) v = *(const float4*)(brow + ng);
          else {
            if (ng   < HD) v.x = brow[ng];
            if (ng+1 < HD) v.y = brow[ng+1];
            if (ng+2 < HD) v.z = brow[ng+2];
          }
        }
        *(float4*)&Bs[bk][n] = v;
      }
    }
    __syncthreads();

    #pragma unroll 8
    for (int k = 0; k < 32; ++k){
      float a[4], bb[4];
      *(float4*)a  = *(const float4*)&As[k][tm*4];
      *(float4*)bb = *(const float4*)&Bs[k][tn*4];
      #pragma unroll
      for (int i = 0; i < 4; ++i)
        #pragma unroll
        for (int j = 0; j < 4; ++j)
          acc[i][j] += a[i]*bb[j];
    }
    __syncthreads();
  }

  #pragma unroll
  for (int i = 0; i < 4; ++i){
    int r = r0 + tm*4 + i;
    #pragma unroll
    for (int j = 0; j < 4; ++j){
      int col = n0 + tn*4 + j;
      if (col < HD) C[(size_t)r * HD + col] = acc[i][j];
    }
  }
}

// ---------------------------------------------------------------------------
// LEVEL-SCHEDULED recurrence, v2: 960 threads (15 waves) per chain.
//   Phase A: pipelined child gather (2-stage prefetch over child list).
//   Phase B: uf_w matvec split 3-way over k (25 float4/thread), partials
//            reduced via LDS pacc[3][8][300].
// RUNS IN PLACE: c over IU, h over Og, g over F0.
// ---------------------------------------------------------------------------
__global__ __launch_bounds__(RTHREADS) void recurrence_k(
    float* IU_C,      // in: IU  / out: c
    float* Og_H,      // in: Og  / out: h
    float* F0_G,      // in: F0  / out: g
    const float* __restrict__ gL, const float* __restrict__ gR,
    const float* __restrict__ ufw)
{
  const int wg   = blockIdx.x;
  const int tree = wg >> 6;
  const int b    = wg & 63;
  const float* graph = tree ? gR : gL;
  const int tid = threadIdx.x;

  __shared__ float  cw  [TD][CMAX];            // 16 KB
  __shared__ unsigned char cidx[TD][CMAX];     // 4 KB
  __shared__ int    ccnt[TD];
  __shared__ int    lvl [TD];
  __shared__ int    cnt [TD+1];
  __shared__ int    cur [TD+1];
  __shared__ int    lvstart[TD+1];
  __shared__ int    order[TD];
  __shared__ int    changed, nlv_s;
  __shared__ __align__(16) float hl[32][HD];   // 38.4 KB
  __shared__ __align__(16) float pacc[3][8][HD]; // 28.8 KB  (total ~91 KB)

  // ---- compact child lists: thread j scans graph row j (tril -> t<j only)
  if (tid < TD){
    const int j = tid;
    const float* grow = graph + ((size_t)b*TD + j)*TD;
    int c = 0;
    for (int t = 0; t < j; ++t){
      float m = grow[t];
      if (m != 0.f && c < CMAX){ cidx[j][c] = (unsigned char)t; cw[j][c] = m; ++c; }
    }
    ccnt[j] = c;
    lvl[j] = 0;
  }
  __syncthreads();

  // ---- levels by Jacobi relaxation (monotone; converges in depth rounds)
  for (int it = 0; it < TD; ++it){
    if (tid == 0) changed = 0;
    __syncthreads();
    if (tid < TD){
      int m = 0, cn = ccnt[tid];
      for (int li = 0; li < cn; ++li){
        int lc = lvl[cidx[tid][li]] + 1;
        m = m > lc ? m : lc;
      }
      if (m > lvl[tid]){ lvl[tid] = m; changed = 1; }
    }
    __syncthreads();
    int ch = changed;
    __syncthreads();            // protect 'changed' before next-iter reset
    if (!ch) break;
  }

  // ---- counting sort by level
  if (tid == 0) nlv_s = 0;
  for (int q = tid; q <= TD; q += RTHREADS){ cnt[q] = 0; }
  __syncthreads();
  if (tid < TD){
    atomicMax(&nlv_s, lvl[tid] + 1);
    atomicAdd(&cnt[lvl[tid]], 1);
  }
  __syncthreads();
  const int nlv = nlv_s;
  if (tid == 0){
    int run = 0;
    for (int lv = 0; lv < nlv; ++lv){
      lvstart[lv] = run; cur[lv] = run; run += cnt[lv];
    }
    lvstart[nlv] = run;   // == TD
  }
  __syncthreads();
  if (tid < TD){
    int p = atomicAdd(&cur[lvl[tid]], 1);
    order[p] = tid;
  }
  __syncthreads();

  const size_t base = (size_t)(tree*BD + b) * TD * HD;

  const int kg = tid / 320;        // 0..2  (k-split group for Phase B)
  const int td = tid - kg*320;     // 0..319

  // ---- main loop over levels
  for (int lv = 0; lv < nlv; ++lv){
    const int s = lvstart[lv], e = lvstart[lv+1];
    const bool doB = (lv != nlv - 1);   // max-level nodes have no parents
    for (int cs0 = s; cs0 < e; cs0 += 32){
      const int csn = (e - cs0) < 32 ? (e - cs0) : 32;

      // Phase A: c,h for all nodes of this chunk (independent; pipelined)
      for (int q = tid; q < csn*HD; q += RTHREADS){
        int ni = q / HD;
        int d  = q - ni*HD;
        int j  = order[cs0 + ni];
        size_t rj = base + (size_t)j*HD + d;
        float f0  = F0_G[rj];
        float acc = 0.f;
        const int cn = ccnt[j];
        if (cn > 0){
          int   t0 = cidx[j][0];
          float w0 = cw[j][0];
          float g0 = F0_G[base + (size_t)t0*HD + d];
          float c0 = IU_C[base + (size_t)t0*HD + d];
          for (int li = 1; li < cn; ++li){
            int   t1 = cidx[j][li];
            float w1 = cw[j][li];
            float g1 = F0_G[base + (size_t)t1*HD + d];
            float c1 = IU_C[base + (size_t)t1*HD + d];
            acc += w0 * sigf(f0 + g0) * c0;
            w0 = w1; g0 = g1; c0 = c1;
          }
          acc += w0 * sigf(f0 + g0) * c0;
        }
        float c = IU_C[rj] + acc;
        float h = Og_H[rj] * tanhf(c);
        IU_C[rj] = c; Og_H[rj] = h; hl[ni][d] = h;
      }
      __syncthreads();

      // Phase B: g = uf_w . h, 8 nodes per pass, 3-way k-split
      if (doB){
        for (int nb0 = 0; nb0 < csn; nb0 += 8){
          if (td < HD){
            const int d = td;
            const float4* wrow = (const float4*)(ufw + (size_t)d * HD) + kg*25;
            float acc[8];
            #pragma unroll
            for (int ni = 0; ni < 8; ++ni) acc[ni] = 0.f;
            #pragma unroll 5
            for (int k4 = 0; k4 < 25; ++k4){
              float4 w = wrow[k4];
              const int kb = kg*100 + k4*4;
              #pragma unroll
              for (int ni = 0; ni < 8; ++ni){
                float4 h4 = *(const float4*)&hl[nb0+ni][kb];
                acc[ni] += w.x*h4.x + w.y*h4.y + w.z*h4.z + w.w*h4.w;
              }
            }
            #pragma unroll
            for (int ni = 0; ni < 8; ++ni) pacc[kg][ni][d] = acc[ni];
          }
          __syncthreads();
          for (int q = tid; q < 8*HD; q += RTHREADS){
            int ni = q / HD;
            int d  = q - ni*HD;
            if (nb0 + ni < csn){
              int j = order[cs0 + nb0 + ni];
              F0_G[base + (size_t)j*HD + d] =
                  pacc[0][ni][d] + pacc[1][ni][d] + pacc[2][ni][d];
            }
          }
          __syncthreads();   // pacc reusable next pass
        }
      } else {
        __syncthreads();     // hl reusable next chunk
      }
    }
  }
}

// ---------------------------------------------------------------------------
// GCN aggregate (A = I + G + G^T, sparse) + relu + max/mean pooling.
// ---------------------------------------------------------------------------
__global__ __launch_bounds__(320) void gcn_pool_k(
    const float* __restrict__ HG,
    const float* __restrict__ gL, const float* __restrict__ gR,
    float* __restrict__ vbuf)
{
  const int wg   = blockIdx.x;
  const int tree = wg >> 6;
  const int b    = wg & 63;
  const float* graph = tree ? gR : gL;
  const int tid = threadIdx.x;

  __shared__ float gl[TD][TD+1];               // 66 KB padded
  __shared__ float aw[TD][AMAX];               // 32 KB
  __shared__ unsigned char ai[TD][AMAX];       // 8 KB
  __shared__ int   acnt[TD];

  for (int q = tid; q < TD*TD; q += 320)
    gl[q >> 7][q & 127] = graph[(size_t)b*TD*TD + q];
  __syncthreads();

  if (tid < TD){
    const int s = tid;
    int c = 0;
    for (int t = 0; t < TD; ++t){
      float w = gl[s][t] + gl[t][s];
      if (w != 0.f && c < AMAX){ ai[s][c] = (unsigned char)t; aw[s][c] = w; ++c; }
    }
    acnt[s] = c;
  }
  __syncthreads();

  const size_t base = (size_t)(tree*BD + b) * TD * HD;
  if (tid < HD){
    float mx = -3.4e38f, sm = 0.f;
    for (int s = 0; s < TD; ++s){
      float v = HG[base + (size_t)s*HD + tid];
      const int cn = acnt[s];
      for (int li = 0; li < cn; ++li)
        v += aw[s][li] * HG[base + (size_t)ai[s][li]*HD + tid];
      v = fmaxf(v, 0.f);
      mx = fmaxf(mx, v);
      sm += v;
    }
    vbuf[(size_t)b*1200 + tree*HD + tid]       = mx;
    vbuf[(size_t)b*1200 + 600 + tree*HD + tid] = sm * (1.f/128.f);
  }
}

// ---------------------------------------------------------------------------
// Classifier: out[b] = wp . relu(wh . v[b] + wh_b) + wp_b
// ---------------------------------------------------------------------------
__global__ __launch_bounds__(320) void classifier_k(
    const float* __restrict__ vbuf,
    const float* __restrict__ wh_w, const float* __restrict__ wh_b,
    const float* __restrict__ wp_w, const float* __restrict__ wp_b,
    float* __restrict__ out)
{
  const int b = blockIdx.x;
  const int tid = threadIdx.x;
  __shared__ __align__(16) float vrow[1200];
  __shared__ float hid[300];
  __shared__ float red[5];

  for (int m = tid; m < 1200; m += 320) vrow[m] = vbuf[(size_t)b*1200 + m];
  __syncthreads();

  if (tid < HD){
    const float4* wrow = (const float4*)(wh_w + (size_t)tid*1200);
    float a0 = wh_b[tid], a1 = 0.f, a2 = 0.f, a3 = 0.f;
    #pragma unroll 5
    for (int m4 = 0; m4 < 300; ++m4){
      float4 w = wrow[m4];
      float4 v = *(const float4*)&vrow[m4*4];
      a0 += w.x*v.x; a1 += w.y*v.y; a2 += w.z*v.z; a3 += w.w*v.w;
    }
    hid[tid] = fmaxf((a0+a1)+(a2+a3), 0.f);
  }
  __syncthreads();

  const int wave = tid >> 6, lane = tid & 63;
  for (int n = 0; n < 3; ++n){
    float p = (tid < HD) ? wp_w[n*HD + tid] * hid[tid] : 0.f;
    #pragma unroll
    for (int off = 32; off > 0; off >>= 1) p += __shfl_down(p, off);
    if (lane == 0) red[wave] = p;
    __syncthreads();
    if (tid == 0){
      float s = wp_b[n];
      for (int wv = 0; wv < 5; ++wv) s += red[wv];
      out[(size_t)b*3 + n] = s;
    }
    __syncthreads();
  }
}

// ---------------------------------------------------------------------------
extern "C" void kernel_launch(void* const* d_in, const int* in_sizes, int n_in,
                              void* d_out, int out_size, void* d_ws, size_t ws_size,
                              hipStream_t stream) {
  const int*   linputs = (const int*)  d_in[0];
  const float* lgraph  = (const float*)d_in[1];
  const int*   rinputs = (const int*)  d_in[2];
  const float* rgraph  = (const float*)d_in[3];
  const float* emb     = (const float*)d_in[4];
  const float* wi_w = (const float*)d_in[5],  *wi_b = (const float*)d_in[6];
  const float* wf_w = (const float*)d_in[7],  *wf_b = (const float*)d_in[8];
  const float* wo_w = (const float*)d_in[9],  *wo_b = (const float*)d_in[10];
  const float* wu_w = (const float*)d_in[11], *wu_b = (const float*)d_in[12];
  const float* ui_b = (const float*)d_in[14];
  const float* uf_w = (const float*)d_in[15], *uf_b = (const float*)d_in[16];
  const float* uo_b = (const float*)d_in[18];
  const float* uu_b = (const float*)d_in[20];
  const float* gcn_w = (const float*)d_in[21];
  const float* wh_w  = (const float*)d_in[22], *wh_b = (const float*)d_in[23];
  const float* wp_w  = (const float*)d_in[24], *wp_b = (const float*)d_in[25];

  // Workspace layout (floats). In-place recurrence: buf0 IU->c, buf1 Og->h,
  // buf2 F0->g. After recurrence buf0 (c) is dead -> reused for HG.
  float* ws   = (float*)d_ws;
  float* buf0 = ws;               // IU -> c -> HG
  float* buf1 = ws + 1*ROWSZ;     // Og -> h
  float* buf2 = ws + 2*ROWSZ;     // F0 -> g
  float* vbuf = ws + 3*ROWSZ;     // 64*1200
  float* out  = (float*)d_out;

  dim3 gg(NROW/64, 5);
  gates_gemm_k<<<gg,256,0,stream>>>(linputs, rinputs, emb,
      wi_w, wf_w, wo_w, wu_w,
      wi_b, ui_b, wf_b, uf_b, wo_b, uo_b, wu_b, uu_b,
      buf0, buf1, buf2);

  recurrence_k<<<128,RTHREADS,0,stream>>>(buf0, buf1, buf2, lgraph, rgraph, uf_w);

  // HG = H @ gcn_w   (H in buf1; HG overwrites buf0 — c is dead)
  gemm_nn_k<<<gg,256,0,stream>>>(buf1, gcn_w, buf0);

  gcn_pool_k<<<128,320,0,stream>>>(buf0, lgraph, rgraph, vbuf);
  classifier_k<<<64,320,0,stream>>>(vbuf, wh_w, wh_b, wp_w, wp_b, out);

  (void)in_sizes; (void)n_in; (void)out_size; (void)ws_size;
}